// Round 3
// baseline (465.808 us; speedup 1.0000x reference)
//
#include <hip/hip_runtime.h>

#define DD 768
#define P 196
#define PP 224          // 7*32, exact — no p/q padding needed
#define NIMG 64
#define NN 32
#define MARGIN 0.5f
#define BK 64           // K-chunk per barrier (128 B per row)
#define NCHUNK 12       // 768/64
#define STRIDE 9        // uint4 per LDS tile row: 8 data + 1 pad (36 words = 4 mod 32)

typedef __bf16 bf16;
typedef __bf16 bf16x4 __attribute__((ext_vector_type(4)));
typedef __bf16 bf16x8 __attribute__((ext_vector_type(8)));   // 16 B MFMA A/B frag
typedef float floatx16 __attribute__((ext_vector_type(16))); // 32x32 MFMA C/D frag

// ---------------------------------------------------------------------------
// Kernel 1: wave-per-row L2-normalize (fp32) -> bf16 into padded [64][224][768].
// Rows 196..223 of each image are zeroed. Also zero-inits the scalar output.
// ---------------------------------------------------------------------------
__global__ __launch_bounds__(256) void norm_kernel(const float* __restrict__ nrm,
                                                   const float* __restrict__ dft,
                                                   bf16* __restrict__ Y,
                                                   float* __restrict__ out) {
    if (blockIdx.x == 0 && threadIdx.x == 0) out[0] = 0.0f;
    int row  = blockIdx.x * 4 + (threadIdx.x >> 6);   // 4 waves/block, 1 row/wave
    int lane = threadIdx.x & 63;
    int img = row / PP, p = row % PP;
    bf16* yr = Y + (size_t)row * DD;
    if (p >= P) {                                     // pad row -> zeros
        bf16x4 z = {(bf16)0.f, (bf16)0.f, (bf16)0.f, (bf16)0.f};
        #pragma unroll
        for (int j = 0; j < 3; ++j) *(bf16x4*)(yr + lane * 4 + j * 256) = z;
        return;
    }
    const float* src = (img < NN) ? nrm + ((size_t)img * P + p) * DD
                                  : dft + ((size_t)(img - NN) * P + p) * DD;
    float4 v[3];
    float ss = 0.f;
    #pragma unroll
    for (int j = 0; j < 3; ++j) {
        v[j] = *(const float4*)(src + lane * 4 + j * 256);
        ss += v[j].x * v[j].x + v[j].y * v[j].y + v[j].z * v[j].z + v[j].w * v[j].w;
    }
    #pragma unroll
    for (int o = 32; o > 0; o >>= 1) ss += __shfl_xor(ss, o);
    float inv = 1.0f / (sqrtf(ss) + 1e-8f);
    #pragma unroll
    for (int j = 0; j < 3; ++j) {
        bf16x4 w;
        w.x = (bf16)(v[j].x * inv);
        w.y = (bf16)(v[j].y * inv);
        w.z = (bf16)(v[j].z * inv);
        w.w = (bf16)(v[j].w * inv);
        *(bf16x4*)(yr + lane * 4 + j * 256) = w;
    }
}

// ---------------------------------------------------------------------------
// Kernel 2: one block per pair (496 nn + 1024 nd), 448 threads = 7 waves.
// Wave w owns p-strip [w*32, w*32+31] x all 224 q via v_mfma_f32_32x32x16_bf16
// (acc = 7 x 16 = 112 VGPRs). Both A and B K-chunks staged in LDS:
//   layout: tile[row*STRIDE + kg8] (uint4), stride 9 -> staging writes and
//   frag reads are both 2 words/bank per 16-lane phase (conflict-free).
// Staging: 2*224*8 = 3584 pieces = 448 threads x 8, fully coalesced
// (8 consecutive lanes = one 128-B line). Global prefetch of chunk c+1 is
// issued before the MFMA phase; MFMAs only wait on lgkmcnt, so the loads
// stay in flight across ~1700 cyc of compute.
// Frag layout (verified R1/R2 on-HW): A/B elem [m=lane&31][k=(lane>>5)*8+j];
// C/D: col q = lane&31, row p = (reg&3) + 8*(reg>>2) + 4*(lane>>5).
// ---------------------------------------------------------------------------
__global__ __launch_bounds__(448, 2) void pair_kernel(const bf16* __restrict__ Y,
                                                      float* __restrict__ out) {
    __shared__ uint4 tiles[2 * PP * STRIDE];   // A: [0,2016), B: [2016,4032) = 63 KB
    __shared__ float redp[7];

    int b = blockIdx.x;
    int ia, ja; bool is_nn;
    if (b < 496) {
        is_nn = true;
        int i = 0, rem = b;
        while (rem >= 31 - i) { rem -= 31 - i; ++i; }   // triangular decode, i<j
        ia = i; ja = i + 1 + rem;
    } else {
        is_nn = false;
        int t = b - 496;
        ia = t >> 5; ja = NN + (t & 31);
    }
    const bf16* Ab = Y + (size_t)ia * PP * DD;
    const bf16* Bb = Y + (size_t)ja * PP * DD;

    int tid   = threadIdx.x;
    int lane  = tid & 63;
    int wave  = tid >> 6;            // 0..6 : p-strip
    int col   = lane & 31;
    int khalf = lane >> 5;           // 0/1 : which 8-k half of the 16-k step

    floatx16 acc[7];
    #pragma unroll
    for (int t = 0; t < 7; ++t)
        #pragma unroll
        for (int r = 0; r < 16; ++r) acc[t][r] = 0.0f;

    uint4 tmp[8];                    // prefetch regs: 4 A-pieces + 4 B-pieces
    auto gload = [&](int c) {
        #pragma unroll
        for (int u = 0; u < 8; ++u) {
            int pc = tid + (u & 3) * 448;            // 0..1791 within matrix
            const bf16* src = (u < 4) ? Ab : Bb;
            tmp[u] = *(const uint4*)(src + (size_t)(pc >> 3) * DD + c * BK + (pc & 7) * 8);
        }
    };
    auto lwrite = [&]() {
        #pragma unroll
        for (int u = 0; u < 8; ++u) {
            int pc = tid + (u & 3) * 448;
            tiles[(u < 4 ? 0 : PP * STRIDE) + (pc >> 3) * STRIDE + (pc & 7)] = tmp[u];
        }
    };

    gload(0);
    for (int c = 0; c < NCHUNK; ++c) {
        lwrite();                      // needs vmcnt drain: overlapped w/ prev MFMAs
        __syncthreads();
        if (c + 1 < NCHUNK) gload(c + 1);   // in flight across the MFMA phase
        const uint4* At = tiles;
        const uint4* Bt = tiles + PP * STRIDE;
        #pragma unroll
        for (int s = 0; s < 4; ++s) {       // 4 k-steps of 16
            int kg = s * 2 + khalf;
            bf16x8 af = *(const bf16x8*)(At + (wave * 32 + col) * STRIDE + kg);
            #pragma unroll
            for (int t = 0; t < 7; ++t) {
                bf16x8 bfr = *(const bf16x8*)(Bt + (t * 32 + col) * STRIDE + kg);
                acc[t] = __builtin_amdgcn_mfma_f32_32x32x16_bf16(af, bfr, acc[t], 0, 0, 0);
            }
        }
        __syncthreads();               // protects tiles before next lwrite
    }

    // column-max over valid p (p<196), per q; alias tiles as colmax[7][224]
    float* cmax = (float*)tiles;
    #pragma unroll
    for (int t = 0; t < 7; ++t) {
        float m = -3.0e38f;
        #pragma unroll
        for (int r = 0; r < 16; ++r) {
            int prow = wave * 32 + (r & 3) + 8 * (r >> 2) + 4 * khalf;
            if (prow < P) m = fmaxf(m, acc[t][r]);
        }
        m = fmaxf(m, __shfl_xor(m, 32));   // merge the two khalf row-sets
        if (khalf == 0) cmax[wave * PP + t * 32 + col] = m;
    }
    __syncthreads();

    float contrib = 0.f;
    if (tid < P) {                         // q >= 196 are pad rows: excluded
        float cm = cmax[tid];
        #pragma unroll
        for (int w = 1; w < 7; ++w) cm = fmaxf(cm, cmax[w * PP + tid]);
        contrib = is_nn ? (1.0f - cm) * (1.0f / (496.0f * 196.0f))
                        : fmaxf(cm - MARGIN, 0.0f) * (1.0f / (1024.0f * 196.0f));
    }
    #pragma unroll
    for (int o = 32; o > 0; o >>= 1) contrib += __shfl_down(contrib, o);
    if (lane == 0) redp[wave] = contrib;
    __syncthreads();
    if (tid == 0) {
        float s = 0.f;
        #pragma unroll
        for (int w = 0; w < 7; ++w) s += redp[w];
        atomicAdd(out, s);
    }
}

// ---------------------------------------------------------------------------
extern "C" void kernel_launch(void* const* d_in, const int* in_sizes, int n_in,
                              void* d_out, int out_size, void* d_ws, size_t ws_size,
                              hipStream_t stream) {
    const float* nrm = (const float*)d_in[0];   // [32,196,768] fp32
    const float* dft = (const float*)d_in[1];   // [32,196,768] fp32
    float* out = (float*)d_out;                 // scalar fp32
    bf16* Y = (bf16*)d_ws;                      // [64,224,768] bf16 = 21.5 MB

    norm_kernel<<<NIMG * PP / 4, 256, 0, stream>>>(nrm, dft, Y, out);
    pair_kernel<<<496 + 1024, 448, 0, stream>>>(Y, out);
}

// Round 4
// 192.371 us; speedup vs baseline: 2.4214x; 2.4214x over previous
//
#include <hip/hip_runtime.h>

#define DD 768
#define P 196
#define PP 224            // rows per image in workspace
#define NIMG 64
#define NN 32
#define MARGIN 0.5f
#define NCH 24            // K-chunks of 32 elements
#define PIECES 896        // 224 rows * 4 pieces (16 B) per chunk per matrix

typedef __bf16 bf16;
typedef __bf16 bf16x8 __attribute__((ext_vector_type(8)));   // 16 B MFMA A/B frag
typedef float floatx4 __attribute__((ext_vector_type(4)));   // 16x16 MFMA C/D frag

typedef __attribute__((address_space(1))) const unsigned char g_u8;
typedef __attribute__((address_space(3))) unsigned char l_u8;

// Workspace Y layout (chunk-major, swizzled):
//   piece(img, c, r, kg') at flat index ((img*24 + c)*896 + r*4 + kg') * 16B
//   data piece kg (elements k = c*32 + kg*8 .. +8) stored at kg' = kg ^ ((r>>1)&3)
// -> staging a chunk = one contiguous 14 KB block (lane-linear, matches the
//    global_load_lds wave-uniform-base + lane*16 constraint), and ds_read_b128
//    frag reads hit each bank exactly twice per 16-lane phase (conflict-free).

// ---------------------------------------------------------------------------
// Kernel 1: wave-per-row L2-normalize (fp32) -> bf16 into swizzled Y.
// Pad rows (p>=196) are left as-is (poison is finite bf16; masked in epilogue).
// Also zero-inits the scalar output.
// ---------------------------------------------------------------------------
__global__ __launch_bounds__(512) void norm_kernel(const float* __restrict__ nrm,
                                                   const float* __restrict__ dft,
                                                   bf16* __restrict__ Y,
                                                   float* __restrict__ out) {
    if (blockIdx.x == 0 && threadIdx.x == 0) out[0] = 0.0f;
    int row  = blockIdx.x * 8 + (threadIdx.x >> 6);
    int lane = threadIdx.x & 63;
    int img = row / PP, p = row % PP;
    if (p >= P) return;
    const float* src = (img < NN) ? nrm + ((size_t)img * P + p) * DD
                                  : dft + ((size_t)(img - NN) * P + p) * DD;
    // lane handles piece `lane` (k=8*lane) and, for lane<32, piece 64+lane
    float4 a0 = *(const float4*)(src + lane * 8);
    float4 a1 = *(const float4*)(src + lane * 8 + 4);
    float4 b0 = {0, 0, 0, 0}, b1 = {0, 0, 0, 0};
    float ss = a0.x * a0.x + a0.y * a0.y + a0.z * a0.z + a0.w * a0.w
             + a1.x * a1.x + a1.y * a1.y + a1.z * a1.z + a1.w * a1.w;
    if (lane < 32) {
        b0 = *(const float4*)(src + 512 + lane * 8);
        b1 = *(const float4*)(src + 512 + lane * 8 + 4);
        ss += b0.x * b0.x + b0.y * b0.y + b0.z * b0.z + b0.w * b0.w
            + b1.x * b1.x + b1.y * b1.y + b1.z * b1.z + b1.w * b1.w;
    }
    #pragma unroll
    for (int o = 32; o > 0; o >>= 1) ss += __shfl_xor(ss, o);
    float inv = 1.0f / (sqrtf(ss) + 1e-8f);

    auto store_piece = [&](int idx, float4 x0, float4 x1) {
        int c = idx >> 2, kg = idx & 3;
        int kgp = kg ^ ((p >> 1) & 3);
        bf16x8 w;
        w[0] = (bf16)(x0.x * inv); w[1] = (bf16)(x0.y * inv);
        w[2] = (bf16)(x0.z * inv); w[3] = (bf16)(x0.w * inv);
        w[4] = (bf16)(x1.x * inv); w[5] = (bf16)(x1.y * inv);
        w[6] = (bf16)(x1.z * inv); w[7] = (bf16)(x1.w * inv);
        *(bf16x8*)(Y + ((size_t)(img * NCH + c) * PIECES + p * 4 + kgp) * 8) = w;
    };
    store_piece(lane, a0, a1);
    if (lane < 32) store_piece(64 + lane, b0, b1);
}

// ---------------------------------------------------------------------------
// Kernel 2: one block per pair (496 nn + 1024 nd), 512 threads = 8 waves in a
// 4x2 grid. Wave (wr,wc): p-rows [wr*64, wr*64+63] (p padded to 256; subtiles
// >=224 read finite garbage, masked in epilogue), q-cols [wc*112, +112).
// Wave tile = 4x7 of 16x16x32 MFMA; acc = 112 regs (AGPRs).
// Staging: global_load_lds width=16 DMA, double-buffered; chunk c+1 issued
// after the frag ds_reads of chunk c, drained by the next barrier.
// ---------------------------------------------------------------------------
__global__ __launch_bounds__(512) void pair_kernel(const bf16* __restrict__ Y,
                                                   float* __restrict__ out) {
    __shared__ uint4 tiles[2][2 * PIECES];   // [buf][A pieces | B pieces] = 56 KB
    __shared__ float colmax[4][PP];
    __shared__ float redp[8];

    int b = blockIdx.x;
    int ia, ja; bool is_nn;
    if (b < 496) {
        is_nn = true;
        int i = 0, rem = b;
        while (rem >= 31 - i) { rem -= 31 - i; ++i; }   // triangular, i<j
        ia = i; ja = i + 1 + rem;
    } else {
        is_nn = false;
        int t = b - 496;
        ia = t & 31;                 // b%8 == ia%8 -> same-A blocks share an XCD
        ja = NN + (t >> 5);
    }

    int tid  = threadIdx.x;
    int lane = tid & 63;
    int wave = tid >> 6;             // 0..7
    int wr   = wave >> 1;            // 0..3 : 64 p-rows
    int wc   = wave & 1;             // 0..1 : 112 q-cols
    int r16  = lane & 15;
    int quad = lane >> 4;            // 0..3 : k-group of 8

    floatx4 acc[4][7];
    #pragma unroll
    for (int ps = 0; ps < 4; ++ps)
        #pragma unroll
        for (int t = 0; t < 7; ++t)
            acc[ps][t] = (floatx4){0.f, 0.f, 0.f, 0.f};

    // stage chunk c of both images into buffer `buf` (1792 pieces of 16 B)
    auto stage = [&](int buf, int c) {
        const bf16* gA = Y + (size_t)(ia * NCH + c) * (PIECES * 8);
        const bf16* gB = Y + (size_t)(ja * NCH + c) * (PIECES * 8);
        #pragma unroll
        for (int u = 0; u < 4; ++u) {
            if (u == 3 && wave >= 4) break;          // 1792 = 3.5 * 512
            int pc0 = u * 512 + wave * 64;           // wave-uniform piece base
            bool isB = pc0 >= PIECES;
            int q0 = isB ? pc0 - PIECES : pc0;
            const bf16* g = (isB ? gB : gA) + (size_t)(q0 + lane) * 8;
            __builtin_amdgcn_global_load_lds((const g_u8*)g,
                                             (l_u8*)&tiles[buf][pc0], 16, 0, 0);
        }
    };

    stage(0, 0);
    for (int c = 0; c < NCH; ++c) {
        __syncthreads();             // drains DMA for chunk c; frees other buf
        const uint4* tb = tiles[c & 1];
        bf16x8 afr[4], bfr[7];
        #pragma unroll
        for (int ps = 0; ps < 4; ++ps) {
            int pr = wr * 64 + ps * 16 + r16;        // 0..255 (>=224: garbage ok)
            afr[ps] = *(const bf16x8*)(tb + pr * 4 + (quad ^ ((pr >> 1) & 3)));
        }
        #pragma unroll
        for (int t = 0; t < 7; ++t) {
            int qr = wc * 112 + t * 16 + r16;        // 0..223
            bfr[t] = *(const bf16x8*)(tb + PIECES + qr * 4 + (quad ^ ((qr >> 1) & 3)));
        }
        if (c + 1 < NCH) stage((c + 1) & 1, c + 1);  // in flight across MFMAs
        #pragma unroll
        for (int ps = 0; ps < 4; ++ps)
            #pragma unroll
            for (int t = 0; t < 7; ++t)
                acc[ps][t] = __builtin_amdgcn_mfma_f32_16x16x32_bf16(
                    afr[ps], bfr[t], acc[ps][t], 0, 0, 0);
    }

    // column-max over valid p (<196) per q. C/D: col q = lane&15, row = quad*4+r
    #pragma unroll
    for (int t = 0; t < 7; ++t) {
        float m = -3.0e38f;
        #pragma unroll
        for (int ps = 0; ps < 4; ++ps) {
            int pbase = wr * 64 + ps * 16 + quad * 4;
            #pragma unroll
            for (int r = 0; r < 4; ++r)
                if (pbase + r < P) m = fmaxf(m, acc[ps][t][r]);
        }
        m = fmaxf(m, __shfl_xor(m, 16));
        m = fmaxf(m, __shfl_xor(m, 32));
        if (quad == 0) colmax[wr][wc * 112 + t * 16 + r16] = m;
    }
    __syncthreads();

    float contrib = 0.f;
    if (tid < P) {
        float cm = fmaxf(fmaxf(colmax[0][tid], colmax[1][tid]),
                         fmaxf(colmax[2][tid], colmax[3][tid]));
        contrib = is_nn ? (1.0f - cm) * (1.0f / (496.0f * 196.0f))
                        : fmaxf(cm - MARGIN, 0.0f) * (1.0f / (1024.0f * 196.0f));
    }
    #pragma unroll
    for (int o = 32; o > 0; o >>= 1) contrib += __shfl_down(contrib, o);
    if (lane == 0) redp[wave] = contrib;
    __syncthreads();
    if (tid == 0) {
        float s = 0.f;
        #pragma unroll
        for (int w = 0; w < 8; ++w) s += redp[w];
        atomicAdd(out, s);
    }
}

// ---------------------------------------------------------------------------
extern "C" void kernel_launch(void* const* d_in, const int* in_sizes, int n_in,
                              void* d_out, int out_size, void* d_ws, size_t ws_size,
                              hipStream_t stream) {
    const float* nrm = (const float*)d_in[0];   // [32,196,768] fp32
    const float* dft = (const float*)d_in[1];   // [32,196,768] fp32
    float* out = (float*)d_out;                 // scalar fp32
    bf16* Y = (bf16*)d_ws;                      // [64][24][896] pieces = 21 MB

    norm_kernel<<<NIMG * PP / 8, 512, 0, stream>>>(nrm, dft, Y, out);
    pair_kernel<<<496 + 1024, 512, 0, stream>>>(Y, out);
}